// Round 5
// baseline (369.837 us; speedup 1.0000x reference)
//
#include <hip/hip_runtime.h>

typedef __attribute__((ext_vector_type(8))) short short8;
typedef __attribute__((ext_vector_type(4))) short short4v;
typedef __attribute__((ext_vector_type(4))) float floatx4;

__device__ __forceinline__ float bf2f(unsigned short u) {
    unsigned int v = ((unsigned int)u) << 16;
    return __builtin_bit_cast(float, v);
}
__device__ __forceinline__ unsigned short f2bf(float f) {
    unsigned int u = __builtin_bit_cast(unsigned int, f);
    u += 0x7fffu + ((u >> 16) & 1u);
    return (unsigned short)(u >> 16);
}

// async global->LDS, 16 B per lane. LDS dest = wave-uniform base + lane*16.
__device__ __forceinline__ void gl_lds16(const void* g, void* l) {
    __builtin_amdgcn_global_load_lds(
        (const __attribute__((address_space(1))) unsigned int*)g,
        (__attribute__((address_space(3))) unsigned int*)l, 16, 0, 0);
}

#define L_DIM 2304
#define D_DIM 512

// ---------------------------------------------------------------------------
// Kernel D: detect input dtype (fp32 vs bf16) from exponent-field statistics.
// ---------------------------------------------------------------------------
__global__ void k_detect(const unsigned short* __restrict__ xs, int* __restrict__ flag) {
    int lane = threadIdx.x;  // 64 threads
    int cnt = 0;
#pragma unroll
    for (int j = 0; j < 16; j++) {
        unsigned short u = xs[2 * (lane * 16 + j)];
        int e = (u >> 7) & 0xFF;
        cnt += (e >= 0xC0) ? 1 : 0;
    }
#pragma unroll
    for (int m = 1; m < 64; m <<= 1) cnt += __shfl_xor(cnt, m);
    if (lane == 0) *flag = (cnt > 4) ? 1 : 0;
}

// ---------------------------------------------------------------------------
// Kernel P: merged prep. Blocks 0..383: convert 3 weight matrices to bf16.
// Block 384: convert 3 biases. Blocks 385..456: zero lsum (if lcount>0).
// ---------------------------------------------------------------------------
__global__ __launch_bounds__(256) void k_prep(
    const void* __restrict__ w0, const void* __restrict__ w1, const void* __restrict__ w2,
    const void* __restrict__ b0, const void* __restrict__ b1, const void* __restrict__ b2,
    short* __restrict__ Wc, short* __restrict__ bc,
    float* __restrict__ lsum, int lcount, const int* __restrict__ flag) {
    const int b = blockIdx.x, tid = threadIdx.x;
    const int fl = *flag;
    if (b < 384) {
        int w = b >> 7, blk = b & 127;
        const void* src = w == 0 ? w0 : (w == 1 ? w1 : w2);
        short* dst = Wc + (size_t)w * 262144;
        int i = (blk * 256 + tid) * 8;
        if (fl) {
            const float* s = (const float*)src + i;
            short8 o;
#pragma unroll
            for (int j = 0; j < 8; j++) o[j] = (short)f2bf(s[j]);
            *(short8*)(dst + i) = o;
        } else {
            *(short8*)(dst + i) = *(const short8*)((const short*)src + i);
        }
    } else if (b == 384) {
        int i = tid * 8;
        if (i < 1536) {
            int which = i >> 9, off = i & 511;
            const void* src = which == 0 ? b0 : (which == 1 ? b1 : b2);
            short* dst = bc + which * 512 + off;
            if (fl) {
                const float* s = (const float*)src + off;
#pragma unroll
                for (int j = 0; j < 8; j++) dst[j] = (short)f2bf(s[j]);
            } else {
#pragma unroll
                for (int j = 0; j < 8; j++) dst[j] = ((const short*)src)[off + j];
            }
        }
    } else {
        int idx = (b - 385) * 256 + tid;
        if (idx < lcount) lsum[idx] = 0.f;
    }
}

// ---------------------------------------------------------------------------
// Kernel 0: transpose x (N, D, L) -> flatX (N, L, D) bf16, 64x64 LDS tiles.
// ---------------------------------------------------------------------------
__global__ __launch_bounds__(256) void k_transpose(const void* __restrict__ x_,
                                                   short* __restrict__ fx,
                                                   const int* __restrict__ flag) {
    __shared__ __align__(16) short t[64 * 72];
    const int n = blockIdx.z, d0 = blockIdx.y * 64, l0 = blockIdx.x * 64;
    const int tid = threadIdx.x;
    if (*flag) {
        const float* x = (const float*)x_;
#pragma unroll
        for (int p = 0; p < 4; p++) {
            int i = tid + p * 256;
            int dr = i >> 4, lc = (i & 15) * 4;
            floatx4 v = *(const floatx4*)(x + (size_t)(n * D_DIM + d0 + dr) * L_DIM + l0 + lc);
#pragma unroll
            for (int j = 0; j < 4; j++) t[(lc + j) * 72 + dr] = (short)f2bf(v[j]);
        }
    } else {
        const short* x = (const short*)x_;
#pragma unroll
        for (int p = 0; p < 2; p++) {
            int i = tid + p * 256;
            int dr = i >> 3, lc = (i & 7) * 8;
            short8 v = *(const short8*)(x + (size_t)(n * D_DIM + d0 + dr) * L_DIM + l0 + lc);
#pragma unroll
            for (int j = 0; j < 8; j++) t[(lc + j) * 72 + dr] = v[j];
        }
    }
    __syncthreads();
#pragma unroll
    for (int p = 0; p < 2; p++) {
        int i = tid + p * 256;
        int lr = i >> 3, dc = (i & 7) * 8;
        short8 v = *(const short8*)&t[lr * 72 + dc];
        *(short8*)(fx + (size_t)(n * L_DIM + l0 + lr) * D_DIM + d0 + dc) = v;
    }
}

// ---------------------------------------------------------------------------
// Kernel TV: transpose V (N, L, F) -> Vt (N, F, L). 64x64 tiles; LDS writes
// packed short4 with l across lanes (2-way conflicts, free).
// ---------------------------------------------------------------------------
__global__ __launch_bounds__(256) void k_trV(const short* __restrict__ src,
                                             short* __restrict__ dst) {
    __shared__ __align__(16) short t[64 * 72];
    const int n = blockIdx.z, l0 = blockIdx.x * 64, f0 = blockIdx.y * 64;
    const int tid = threadIdx.x;
    if (tid < 128) {
        const int ll = (tid & 15) * 4;
        const int ff = (tid >> 4) * 8;
        short8 v[4];
#pragma unroll
        for (int r = 0; r < 4; r++)
            v[r] = *(const short8*)(src + (size_t)(n * L_DIM + l0 + ll + r) * D_DIM + f0 + ff);
#pragma unroll
        for (int j = 0; j < 8; j++) {
            short4v w = { v[0][j], v[1][j], v[2][j], v[3][j] };
            *(short4v*)&t[(ff + j) * 72 + ll] = w;
        }
    }
    __syncthreads();
#pragma unroll
    for (int p = 0; p < 2; p++) {
        int i = tid + p * 256;
        int fr = i >> 3, lc = (i & 7) * 8;
        short8 o = *(const short8*)&t[fr * 72 + lc];
        *(short8*)(dst + (size_t)(n * D_DIM + f0 + fr) * L_DIM + l0 + lc) = o;
    }
}

// ---------------------------------------------------------------------------
// Shared GEMM core: C(128x128) += A(l0.., :) * B^T(f0.., :), bf16, BK=32,
// 256 threads = 4 waves (2x2), wave = 64x64 = 4x4 16x16x32 MFMA.
// Row strides lda/ldb; K-range [kBeg, kEnd). global_load_lds width-16 staging.
// ---------------------------------------------------------------------------
__device__ __forceinline__ void gemm128(const short* __restrict__ A,
                                        const short* __restrict__ B,
                                        int lda, int ldb, int kBeg, int kEnd,
                                        int l0, int f0,
                                        short* ldsA, short* ldsB,
                                        floatx4 acc[4][4]) {
    const int tid = threadIdx.x, lane = tid & 63, wid = tid >> 6;
    const int wm = wid & 1, wn = wid >> 1, quad = lane >> 4, l16 = lane & 15;
    const int r16 = lane >> 2, c8 = (lane & 3) * 8;
    for (int kt = kBeg; kt < kEnd; kt += 32) {
        __syncthreads();
#pragma unroll
        for (int p = 0; p < 2; p++) {
            int row = (wid + p * 4) * 16;
            gl_lds16(A + (size_t)(l0 + row + r16) * lda + kt + c8, ldsA + row * 32);
            gl_lds16(B + (size_t)(f0 + row + r16) * ldb + kt + c8, ldsB + row * 32);
        }
        __syncthreads();
        short8 a[4], b[4];
#pragma unroll
        for (int mi = 0; mi < 4; mi++)
            a[mi] = *(const short8*)&ldsA[(wm * 64 + mi * 16 + l16) * 32 + quad * 8];
#pragma unroll
        for (int ni = 0; ni < 4; ni++)
            b[ni] = *(const short8*)&ldsB[(wn * 64 + ni * 16 + l16) * 32 + quad * 8];
#pragma unroll
        for (int mi = 0; mi < 4; mi++)
#pragma unroll
            for (int ni = 0; ni < 4; ni++)
                acc[mi][ni] = __builtin_amdgcn_mfma_f32_16x16x32_bf16(a[mi], b[ni], acc[mi][ni], 0, 0, 0);
    }
}

// ---------------------------------------------------------------------------
// Kernel 1: P = tanh(flatX @ W^T + b). 1D grid 1728; n = bx & 7 pins each
// batch to one XCD (dispatch round-robin) for L2 locality.
// ---------------------------------------------------------------------------
__global__ __launch_bounds__(256) void k_gemm_proj(const short* __restrict__ fx,
                                                   const short* __restrict__ Wc,
                                                   const short* __restrict__ bc,
                                                   short* __restrict__ Pbase) {
    __shared__ __align__(16) short ldsA[128 * 32];
    __shared__ __align__(16) short ldsB[128 * 32];
    const int bx = blockIdx.x;
    const int n = bx & 7, t = bx >> 3;
    const int proj = t / 72, tt = t % 72;
    const int l0 = (tt >> 2) * 128, f0 = (tt & 3) * 128;
    const short* A = fx + (size_t)n * L_DIM * D_DIM;
    const short* B = Wc + (size_t)proj * 262144;
    const short* bias = bc + proj * 512;
    short* P = Pbase + (size_t)proj * 8 * L_DIM * D_DIM + (size_t)n * L_DIM * D_DIM;
    const int lane = threadIdx.x & 63, wid = threadIdx.x >> 6;
    const int wm = wid & 1, wn = wid >> 1, quad = lane >> 4, l16 = lane & 15;

    floatx4 acc[4][4] = {};
    gemm128(A, B, 512, 512, 0, 512, l0, f0, ldsA, ldsB, acc);

#pragma unroll
    for (int ni = 0; ni < 4; ni++) {
        int f = f0 + wn * 64 + ni * 16 + l16;
        float bb = bf2f((unsigned short)bias[f]);
#pragma unroll
        for (int mi = 0; mi < 4; mi++) {
#pragma unroll
            for (int r = 0; r < 4; r++) {
                int l = l0 + wm * 64 + mi * 16 + quad * 4 + r;
                float v = tanhf(acc[mi][ni][r] + bb);
                P[(size_t)l * 512 + f] = (short)f2bf(v);
            }
        }
    }
}

// ---------------------------------------------------------------------------
// Kernel 2: in-place double instance-norm over each 512-feature row.
// ---------------------------------------------------------------------------
__global__ __launch_bounds__(256) void k_norm(short* __restrict__ base) {
    const int row = blockIdx.x * 4 + (threadIdx.x >> 6);
    const int lane = threadIdx.x & 63;
    short* p = base + (size_t)row * 512 + lane * 8;
    short8 v = *(const short8*)p;
    float x[8], s = 0.f, sq = 0.f;
#pragma unroll
    for (int j = 0; j < 8; j++) {
        x[j] = bf2f((unsigned short)v[j]);
        s += x[j];
        sq += x[j] * x[j];
    }
#pragma unroll
    for (int m = 1; m < 64; m <<= 1) {
        s += __shfl_xor(s, m);
        sq += __shfl_xor(sq, m);
    }
    float mu = s * (1.0f / 512.0f);
    float var = sq * (1.0f / 512.0f) - mu * mu;
    float r1 = rsqrtf(var + 1e-5f);
    float y[8], s2 = 0.f, sq2 = 0.f;
#pragma unroll
    for (int j = 0; j < 8; j++) {
        y[j] = (x[j] - mu) * r1;
        s2 += y[j];
        sq2 += y[j] * y[j];
    }
#pragma unroll
    for (int m = 1; m < 64; m <<= 1) {
        s2 += __shfl_xor(s2, m);
        sq2 += __shfl_xor(sq2, m);
    }
    float mu2 = s2 * (1.0f / 512.0f);
    float var2 = sq2 * (1.0f / 512.0f) - mu2 * mu2;
    float r2 = rsqrtf(var2 + 1e-5f);
    short8 o;
#pragma unroll
    for (int j = 0; j < 8; j++) o[j] = (short)f2bf((y[j] - mu2) * r2);
    *(short8*)p = o;
}

// ---------------------------------------------------------------------------
// Kernel 3a: P = exp(Q K^T / sqrt(512)) bf16 + row-sum atomics.
// 1D grid 2592; n = bx & 7 -> one batch per XCD. Plain P stores (the
// out-GEMM on the same XCD re-reads P from L2/L3).
// ---------------------------------------------------------------------------
__global__ __launch_bounds__(256) void k_gemm_scores(const short* __restrict__ Q,
                                                     const short* __restrict__ Kb,
                                                     short* __restrict__ P,
                                                     float* __restrict__ lsum) {
    __shared__ __align__(16) short ldsA[128 * 32];
    __shared__ __align__(16) short ldsB[128 * 32];
    const int bx = blockIdx.x;
    const int n = bx & 7, t = bx >> 3;
    const int l0 = (t / 18) * 128, m0 = (t % 18) * 128;
    const short* A = Q + (size_t)n * L_DIM * D_DIM;
    const short* B = Kb + (size_t)n * L_DIM * D_DIM;
    const int lane = threadIdx.x & 63, wid = threadIdx.x >> 6;
    const int wm = wid & 1, wn = wid >> 1, quad = lane >> 4, l16 = lane & 15;

    floatx4 acc[4][4] = {};
    gemm128(A, B, 512, 512, 0, 512, l0, m0, ldsA, ldsB, acc);

    const float sc = 0.044194173824159216f;  // 1/sqrt(512)
    short* Pn = P + (size_t)n * L_DIM * L_DIM;
    float* ln = lsum + n * L_DIM;
#pragma unroll
    for (int mi = 0; mi < 4; mi++) {
#pragma unroll
        for (int r = 0; r < 4; r++) {
            int row = l0 + wm * 64 + mi * 16 + quad * 4 + r;
            float s = 0.f;
#pragma unroll
            for (int ni = 0; ni < 4; ni++) {
                int col = m0 + wn * 64 + ni * 16 + l16;
                unsigned short pb = f2bf(__expf(acc[mi][ni][r] * sc));
                Pn[(size_t)row * L_DIM + col] = (short)pb;
                s += bf2f(pb);  // denominator consistent with bf16-rounded P
            }
            s += __shfl_xor(s, 1);
            s += __shfl_xor(s, 2);
            s += __shfl_xor(s, 4);
            s += __shfl_xor(s, 8);
            if (l16 == 0) atomicAdd(&ln[row], s);
        }
    }
}

// ---------------------------------------------------------------------------
// Kernel 3b: split-K=2 partial GEMM: part[s] = P[:, ks..ks+1152) @ V-half.
// 1D grid 1152; bx -> n = bx & 7 (XCD pin), t = bx>>3: l-tile (18) x f-tile
// (4) x split (2). Raw fp32 partial tiles; epilogue moved to k_combine.
// ---------------------------------------------------------------------------
__global__ __launch_bounds__(256) void k_gemm_out_sk(const short* __restrict__ P,
                                                     const short* __restrict__ Vt,
                                                     float* __restrict__ part) {
    __shared__ __align__(16) short ldsA[128 * 32];
    __shared__ __align__(16) short ldsB[128 * 32];
    const int bx = blockIdx.x;
    const int n = bx & 7, t = bx >> 3;
    const int l0 = (t >> 3) * 128;
    const int rem = t & 7;
    const int f0 = (rem >> 1) * 128, s = rem & 1;
    const short* A = P + (size_t)n * L_DIM * L_DIM;
    const short* B = Vt + (size_t)n * D_DIM * L_DIM;
    const int lane = threadIdx.x & 63, wid = threadIdx.x >> 6;
    const int wm = wid & 1, wn = wid >> 1, quad = lane >> 4, l16 = lane & 15;

    floatx4 acc[4][4] = {};
    gemm128(A, B, L_DIM, L_DIM, s * 1152, s * 1152 + 1152, l0, f0, ldsA, ldsB, acc);

    float* pp = part + (size_t)s * 8 * L_DIM * D_DIM;
#pragma unroll
    for (int mi = 0; mi < 4; mi++) {
#pragma unroll
        for (int r = 0; r < 4; r++) {
            int row = l0 + wm * 64 + mi * 16 + quad * 4 + r;
#pragma unroll
            for (int ni = 0; ni < 4; ni++) {
                int f = f0 + wn * 64 + ni * 16 + l16;
                pp[((size_t)n * L_DIM + row) * 512 + f] = acc[mi][ni][r];
            }
        }
    }
}

// ---------------------------------------------------------------------------
// Kernel 3c: out = (part0 + part1) / lsum, cast per flag. BW-bound.
// grid 4608, 8 elems/thread.
// ---------------------------------------------------------------------------
__global__ __launch_bounds__(256) void k_combine(const float* __restrict__ part,
                                                 const float* __restrict__ lsum,
                                                 void* __restrict__ out_,
                                                 const int* __restrict__ flag) {
    const size_t half = (size_t)8 * L_DIM * D_DIM;
    size_t i = ((size_t)blockIdx.x * 256 + threadIdx.x) * 8;
    int row = (int)(i >> 9);
    float rl = 1.0f / lsum[row];
    floatx4 a0 = *(const floatx4*)(part + i);
    floatx4 a1 = *(const floatx4*)(part + i + 4);
    floatx4 b0 = *(const floatx4*)(part + half + i);
    floatx4 b1 = *(const floatx4*)(part + half + i + 4);
    if (*flag) {
        float* out = (float*)out_;
        floatx4 o0, o1;
#pragma unroll
        for (int j = 0; j < 4; j++) {
            o0[j] = (a0[j] + b0[j]) * rl;
            o1[j] = (a1[j] + b1[j]) * rl;
        }
        *(floatx4*)(out + i) = o0;
        *(floatx4*)(out + i + 4) = o1;
    } else {
        short* out = (short*)out_;
        short8 o;
#pragma unroll
        for (int j = 0; j < 4; j++) {
            o[j] = (short)f2bf((a0[j] + b0[j]) * rl);
            o[j + 4] = (short)f2bf((a1[j] + b1[j]) * rl);
        }
        *(short8*)(out + i) = o;
    }
}

// ---------------------------------------------------------------------------
// FALLBACK fused attention (round-2 version, known correct) for small ws.
// ---------------------------------------------------------------------------
__global__ __launch_bounds__(512) void k_attn(const short* __restrict__ Q,
                                              const short* __restrict__ K,
                                              const short* __restrict__ V,
                                              void* __restrict__ out_,
                                              const int* __restrict__ flag) {
    __shared__ __align__(16) short ldsKV[512 * 40];
    __shared__ __align__(16) short ldsP[64 * 40];
    __shared__ float ldsL[64];
    const int n = blockIdx.y;
    const int q0 = blockIdx.x * 64;
    const int tid = threadIdx.x, lane = tid & 63, wid = tid >> 6;
    const int wq = wid & 3, wk = wid >> 2, quad = lane >> 4, l16 = lane & 15;
    const short* Qn = Q + (size_t)n * L_DIM * 512;
    const short* Kn = K + (size_t)n * L_DIM * 512;
    const short* Vn = V + (size_t)n * L_DIM * 512;
    if (tid < 64) ldsL[tid] = 0.f;

    short8 qf[16];
#pragma unroll
    for (int fs = 0; fs < 16; fs++)
        qf[fs] = *(const short8*)(Qn + (size_t)(q0 + wq * 16 + l16) * 512 + fs * 32 + quad * 8);

    floatx4 acc[16] = {};
    const float sc = 0.044194173824159216f;

    for (int kt = 0; kt < 72; kt++) {
        const int key0 = kt * 32;
        __syncthreads();
#pragma unroll
        for (int p = 0; p < 4; p++) {
            int i = tid + p * 512;
            int row = i >> 6, c = (i & 63) * 8;
            *(short8*)&ldsKV[row * 520 + c] =
                *(const short8*)(Kn + (size_t)(key0 + row) * 512 + c);
        }
        __syncthreads();
        floatx4 sacc = {0.f, 0.f, 0.f, 0.f};
#pragma unroll
        for (int fs = 0; fs < 16; fs++) {
            short8 kf = *(const short8*)&ldsKV[(wk * 16 + l16) * 520 + fs * 32 + quad * 8];
            sacc = __builtin_amdgcn_mfma_f32_16x16x32_bf16(qf[fs], kf, sacc, 0, 0, 0);
        }
        float pe[4];
#pragma unroll
        for (int r = 0; r < 4; r++) {
            unsigned short pb = f2bf(__expf(sacc[r] * sc));
            ldsP[(wq * 16 + quad * 4 + r) * 40 + wk * 16 + l16] = (short)pb;
            pe[r] = bf2f(pb);
        }
#pragma unroll
        for (int r = 0; r < 4; r++) {
            float s = pe[r];
            s += __shfl_xor(s, 1);
            s += __shfl_xor(s, 2);
            s += __shfl_xor(s, 4);
            s += __shfl_xor(s, 8);
            if (l16 == 0) atomicAdd(&ldsL[wq * 16 + quad * 4 + r], s);
        }
        __syncthreads();
#pragma unroll
        for (int p = 0; p < 4; p++) {
            int i = tid + p * 512;
            int row = i >> 6, c = (i & 63) * 8;
            short8 v = *(const short8*)(Vn + (size_t)(key0 + row) * 512 + c);
#pragma unroll
            for (int j = 0; j < 8; j++) ldsKV[(c + j) * 40 + row] = v[j];
        }
        __syncthreads();
        short8 pf = *(const short8*)&ldsP[(wq * 16 + l16) * 40 + quad * 8];
#pragma unroll
        for (int ni = 0; ni < 16; ni++) {
            short8 vf = *(const short8*)&ldsKV[(wk * 256 + ni * 16 + l16) * 40 + quad * 8];
            acc[ni] = __builtin_amdgcn_mfma_f32_16x16x32_bf16(pf, vf, acc[ni], 0, 0, 0);
        }
    }
    __syncthreads();
    float rl[4];
#pragma unroll
    for (int r = 0; r < 4; r++) rl[r] = 1.0f / ldsL[wq * 16 + quad * 4 + r];
    if (*flag) {
        float* out = (float*)out_;
#pragma unroll
        for (int ni = 0; ni < 16; ni++) {
            int f = wk * 256 + ni * 16 + l16;
#pragma unroll
            for (int r = 0; r < 4; r++) {
                int q = q0 + wq * 16 + quad * 4 + r;
                out[((size_t)n * L_DIM + q) * 512 + f] = acc[ni][r] * rl[r];
            }
        }
    } else {
        short* out = (short*)out_;
#pragma unroll
        for (int ni = 0; ni < 16; ni++) {
            int f = wk * 256 + ni * 16 + l16;
#pragma unroll
            for (int r = 0; r < 4; r++) {
                int q = q0 + wq * 16 + quad * 4 + r;
                out[((size_t)n * L_DIM + q) * 512 + f] = (short)f2bf(acc[ni][r] * rl[r]);
            }
        }
    }
}

extern "C" void kernel_launch(void* const* d_in, const int* in_sizes, int n_in,
                              void* d_out, int out_size, void* d_ws, size_t ws_size,
                              hipStream_t stream) {
    char* ws = (char*)d_ws;
    const size_t S1 = (size_t)8 * L_DIM * D_DIM * sizeof(short);  // 18,874,368
    int* flag = (int*)ws;
    short* Wc = (short*)(ws + 4096);
    short* bc = (short*)(ws + 4096 + 3 * 262144 * 2);
    short* flatX = (short*)(ws + 1581056);
    short* Pq = (short*)((char*)flatX + S1);
    short* Pk = (short*)((char*)Pq + S1);
    short* Pv = (short*)((char*)Pk + S1);

    const size_t need = 1581056 + 5 * S1 + 73728 + (size_t)8 * L_DIM * L_DIM * 2;
    const bool big = ws_size >= need;
    short* Vt = (short*)((char*)Pv + S1);
    float* lsum = (float*)((char*)Vt + S1);
    short* P = (short*)((char*)lsum + 73728);
    // Split-K partials (2 x 37.7 MB fp32) overlay flatX..Pv (dead by then).
    float* part = (float*)flatX;

    k_detect<<<1, 64, 0, stream>>>((const unsigned short*)d_in[0], flag);
    k_prep<<<457, 256, 0, stream>>>(d_in[1], d_in[3], d_in[5], d_in[2], d_in[4], d_in[6],
                                    Wc, bc, lsum, big ? 18432 : 0, flag);
    k_transpose<<<dim3(36, 8, 8), 256, 0, stream>>>(d_in[0], flatX, flag);
    k_gemm_proj<<<1728, 256, 0, stream>>>(flatX, Wc, bc, Pq);
    k_norm<<<13824, 256, 0, stream>>>(Pq);  // Q,K,V contiguous

    if (big) {
        k_trV<<<dim3(36, 8, 8), 256, 0, stream>>>(Pv, Vt);
        k_gemm_scores<<<2592, 256, 0, stream>>>(Pq, Pk, P, lsum);
        k_gemm_out_sk<<<1152, 256, 0, stream>>>(P, Vt, part);
        k_combine<<<4608, 256, 0, stream>>>(part, lsum, d_out, flag);
    } else {
        k_attn<<<dim3(36, 8), 512, 0, stream>>>(Pq, Pk, Pv, d_out, flag);
    }
}

// Round 7
// 307.965 us; speedup vs baseline: 1.2009x; 1.2009x over previous
//
#include <hip/hip_runtime.h>

typedef __attribute__((ext_vector_type(8))) short short8;
typedef __attribute__((ext_vector_type(4))) short short4v;
typedef __attribute__((ext_vector_type(4))) float floatx4;

__device__ __forceinline__ float bf2f(unsigned short u) {
    unsigned int v = ((unsigned int)u) << 16;
    return __builtin_bit_cast(float, v);
}
__device__ __forceinline__ unsigned short f2bf(float f) {
    unsigned int u = __builtin_bit_cast(unsigned int, f);
    u += 0x7fffu + ((u >> 16) & 1u);
    return (unsigned short)(u >> 16);
}

// async global->LDS, 16 B per lane. LDS dest = wave-uniform base + lane*16.
__device__ __forceinline__ void gl_lds16(const void* g, void* l) {
    __builtin_amdgcn_global_load_lds(
        (const __attribute__((address_space(1))) unsigned int*)g,
        (__attribute__((address_space(3))) unsigned int*)l, 16, 0, 0);
}

#define L_DIM 2304
#define D_DIM 512

// Inline dtype detect: 128 samples of x's even uint16s. bf16 N(0,1) never has
// exponent field >= 0xC0; fp32 low-mantissa halves hit it ~25% of the time.
__device__ __forceinline__ int detect_f32(const unsigned short* __restrict__ xs) {
    int lane = threadIdx.x & 63;
    int c = 0;
    unsigned short u0 = xs[2 * lane];
    unsigned short u1 = xs[128 + 2 * lane];
    c += (((u0 >> 7) & 0xFF) >= 0xC0) ? 1 : 0;
    c += (((u1 >> 7) & 0xFF) >= 0xC0) ? 1 : 0;
#pragma unroll
    for (int m = 1; m < 64; m <<= 1) c += __shfl_xor(c, m);
    return c > 8;
}

// ---------------------------------------------------------------------------
// Kernel PRE: merged prep. Blocks 0..383 weight convert; 384 biases;
// 385..456 zero lsum; 457..2760 transpose x (N,D,L)->(N,L,D) 64x64 tiles.
// ---------------------------------------------------------------------------
__global__ __launch_bounds__(256) void k_pre(
    const void* __restrict__ w0, const void* __restrict__ w1, const void* __restrict__ w2,
    const void* __restrict__ b0, const void* __restrict__ b1, const void* __restrict__ b2,
    const void* __restrict__ x_, const unsigned short* __restrict__ xs,
    short* __restrict__ Wc, short* __restrict__ bc,
    float* __restrict__ lsum, short* __restrict__ fx) {
    __shared__ __align__(16) short t[64 * 72];
    const int b = blockIdx.x, tid = threadIdx.x;
    const int fl = detect_f32(xs);
    if (b < 384) {
        int w = b >> 7, blk = b & 127;
        const void* src = w == 0 ? w0 : (w == 1 ? w1 : w2);
        short* dst = Wc + (size_t)w * 262144;
        int i = (blk * 256 + tid) * 8;
        if (fl) {
            const float* s = (const float*)src + i;
            short8 o;
#pragma unroll
            for (int j = 0; j < 8; j++) o[j] = (short)f2bf(s[j]);
            *(short8*)(dst + i) = o;
        } else {
            *(short8*)(dst + i) = *(const short8*)((const short*)src + i);
        }
    } else if (b == 384) {
        int i = tid * 8;
        if (i < 1536) {
            int which = i >> 9, off = i & 511;
            const void* src = which == 0 ? b0 : (which == 1 ? b1 : b2);
            short* dst = bc + which * 512 + off;
            if (fl) {
                const float* s = (const float*)src + off;
#pragma unroll
                for (int j = 0; j < 8; j++) dst[j] = (short)f2bf(s[j]);
            } else {
#pragma unroll
                for (int j = 0; j < 8; j++) dst[j] = ((const short*)src)[off + j];
            }
        }
    } else if (b < 457) {
        int idx = (b - 385) * 256 + tid;
        if (idx < 18432) lsum[idx] = 0.f;
    } else {
        int bb = b - 457;  // 0..2303
        int n = bb & 7, q = bb >> 3;           // q 0..287
        int d0 = (q & 7) * 64, l0 = (q >> 3) * 64;
        if (fl) {
            const float* x = (const float*)x_;
#pragma unroll
            for (int p = 0; p < 4; p++) {
                int i = tid + p * 256;
                int dr = i >> 4, lc = (i & 15) * 4;
                floatx4 v = *(const floatx4*)(x + (size_t)(n * D_DIM + d0 + dr) * L_DIM + l0 + lc);
#pragma unroll
                for (int j = 0; j < 4; j++) t[(lc + j) * 72 + dr] = (short)f2bf(v[j]);
            }
        } else {
            const short* x = (const short*)x_;
#pragma unroll
            for (int p = 0; p < 2; p++) {
                int i = tid + p * 256;
                int dr = i >> 3, lc = (i & 7) * 8;
                short8 v = *(const short8*)(x + (size_t)(n * D_DIM + d0 + dr) * L_DIM + l0 + lc);
#pragma unroll
                for (int j = 0; j < 8; j++) t[(lc + j) * 72 + dr] = v[j];
            }
        }
        __syncthreads();
#pragma unroll
        for (int p = 0; p < 2; p++) {
            int i = tid + p * 256;
            int lr = i >> 3, dc = (i & 7) * 8;
            short8 v = *(const short8*)&t[lr * 72 + dc];
            *(short8*)(fx + (size_t)(n * L_DIM + l0 + lr) * D_DIM + d0 + dc) = v;
        }
    }
}

// ---------------------------------------------------------------------------
// Kernel PROJNORM: fused  P = inorm(inorm(tanh(flatX @ W^T + b)))  per row.
// Block = 64 l-rows x full 512 f, 256 threads = 4 waves, wave = 64 x 128
// (acc[4][8]). Rows block-complete -> both norms in epilogue; second norm
// is analytic (mean(y)=0, var(y)=var/(var+eps)). proj 0/1 store row-major;
// proj 2 stores transposed Vt via LDS chunk transpose (stride 72 = 16B-mult).
// LDS: A 4096 B | B 32768 B = 36864 B exactly.
// grid 864: n = bx & 7 (XCD), t = bx>>3, proj = t/36, l-tile = t%36.
// ---------------------------------------------------------------------------
__global__ __launch_bounds__(256, 2) void k_projnorm(
    const short* __restrict__ fx, const short* __restrict__ Wc,
    const short* __restrict__ bc, short* __restrict__ Pq,
    short* __restrict__ Pk, short* __restrict__ Vt) {
    __shared__ __align__(16) char lds[36864];     // A 4KB | B 32KB ; reused as tr
    __shared__ float rsum[64], rsq[64];
    short* ldsA = (short*)lds;                    // 64 x 32
    short* ldsB = (short*)(lds + 4096);           // 512 x 32
    const int bx = blockIdx.x;
    const int n = bx & 7, t = bx >> 3;            // t 0..107
    const int proj = t / 36, l0 = (t % 36) * 64;
    const short* A = fx + (size_t)n * L_DIM * D_DIM;
    const short* W = Wc + (size_t)proj * 262144;
    const short* bias = bc + proj * 512;
    const int tid = threadIdx.x, lane = tid & 63, wid = tid >> 6;
    const int quad = lane >> 4, l16 = lane & 15;
    const int r16 = lane >> 2, c8 = (lane & 3) * 8;

    floatx4 acc[4][8] = {};
    for (int kt = 0; kt < 512; kt += 32) {
        __syncthreads();
        // A tile 64x32 (4 KB): wave w stages rows [w*16, w*16+16)
        gl_lds16(A + (size_t)(l0 + wid * 16 + r16) * 512 + kt + c8, ldsA + wid * 16 * 32);
        // B tile 512x32 (32 KB): 8 passes
#pragma unroll
        for (int p = 0; p < 8; p++) {
            int row = (p * 4 + wid) * 16;
            gl_lds16(W + (size_t)(row + r16) * 512 + kt + c8, ldsB + row * 32);
        }
        __syncthreads();
        short8 a[4], bf[8];
#pragma unroll
        for (int mi = 0; mi < 4; mi++)
            a[mi] = *(const short8*)&ldsA[(mi * 16 + l16) * 32 + quad * 8];
#pragma unroll
        for (int ni = 0; ni < 8; ni++)
            bf[ni] = *(const short8*)&ldsB[(wid * 128 + ni * 16 + l16) * 32 + quad * 8];
#pragma unroll
        for (int mi = 0; mi < 4; mi++)
#pragma unroll
            for (int ni = 0; ni < 8; ni++)
                acc[mi][ni] = __builtin_amdgcn_mfma_f32_16x16x32_bf16(a[mi], bf[ni], acc[mi][ni], 0, 0, 0);
    }
    __syncthreads();
    if (tid < 64) { rsum[tid] = 0.f; rsq[tid] = 0.f; }
    float bb[8];
#pragma unroll
    for (int ni = 0; ni < 8; ni++) bb[ni] = bf2f((unsigned short)bias[wid * 128 + ni * 16 + l16]);
    // in-place tanh: tanh(v) = 1 - 2/(exp(2v)+1)
#pragma unroll
    for (int mi = 0; mi < 4; mi++)
#pragma unroll
        for (int ni = 0; ni < 8; ni++)
#pragma unroll
            for (int r = 0; r < 4; r++) {
                float v = acc[mi][ni][r] + bb[ni];
                float e = __expf(2.0f * v);
                acc[mi][ni][r] = 1.0f - 2.0f / (e + 1.0f);
            }
    __syncthreads();  // rsum/rsq zeroed
#pragma unroll
    for (int mi = 0; mi < 4; mi++)
#pragma unroll
        for (int r = 0; r < 4; r++) {
            float s = 0.f, q = 0.f;
#pragma unroll
            for (int ni = 0; ni < 8; ni++) {
                float v = acc[mi][ni][r];
                s += v;
                q += v * v;
            }
            s += __shfl_xor(s, 1); q += __shfl_xor(q, 1);
            s += __shfl_xor(s, 2); q += __shfl_xor(q, 2);
            s += __shfl_xor(s, 4); q += __shfl_xor(q, 4);
            s += __shfl_xor(s, 8); q += __shfl_xor(q, 8);
            if (l16 == 0) {
                int row = mi * 16 + quad * 4 + r;
                atomicAdd(&rsum[row], s);
                atomicAdd(&rsq[row], q);
            }
        }
    __syncthreads();
    // normalize in place: z = (v - mu) * r1 * rsqrt(var/(var+eps) + eps)
#pragma unroll
    for (int mi = 0; mi < 4; mi++)
#pragma unroll
        for (int r = 0; r < 4; r++) {
            int row = mi * 16 + quad * 4 + r;
            float mu = rsum[row] * (1.0f / 512.0f);
            float var = rsq[row] * (1.0f / 512.0f) - mu * mu;
            float r1 = rsqrtf(var + 1e-5f);
            float v2 = var * r1 * r1;
            float sc = r1 * rsqrtf(v2 + 1e-5f);
#pragma unroll
            for (int ni = 0; ni < 8; ni++)
                acc[mi][ni][r] = (acc[mi][ni][r] - mu) * sc;
        }
    if (proj < 2) {
        short* Pd = (proj == 0 ? Pq : Pk) + (size_t)n * L_DIM * 512;
#pragma unroll
        for (int mi = 0; mi < 4; mi++)
#pragma unroll
            for (int r = 0; r < 4; r++) {
                int l = l0 + mi * 16 + quad * 4 + r;
#pragma unroll
                for (int ni = 0; ni < 8; ni++) {
                    int f = wid * 128 + ni * 16 + l16;
                    Pd[(size_t)l * 512 + f] = (short)f2bf(acc[mi][ni][r]);
                }
            }
    } else {
        // transposed store via LDS: 4 chunks of 128 f x 64 l, stride 72
        short* tr = (short*)lds;
        for (int c = 0; c < 4; c++) {
            __syncthreads();
            if (wid == c) {
#pragma unroll
                for (int mi = 0; mi < 4; mi++)
#pragma unroll
                    for (int ni = 0; ni < 8; ni++)
#pragma unroll
                        for (int r = 0; r < 4; r++)
                            tr[(ni * 16 + l16) * 72 + mi * 16 + quad * 4 + r] =
                                (short)f2bf(acc[mi][ni][r]);
            }
            __syncthreads();
#pragma unroll
            for (int p = 0; p < 4; p++) {
                int fr = p * 32 + (tid >> 3), lc = (tid & 7) * 8;
                short8 o = *(const short8*)&tr[fr * 72 + lc];
                *(short8*)(Vt + ((size_t)(n * 512 + c * 128 + fr)) * L_DIM + l0 + lc) = o;
            }
        }
    }
}

// ---------------------------------------------------------------------------
// Shared GEMM core: C(128x128) += A * B^T, bf16, BK=32, 256 threads = 4 waves
// (2x2), wave 64x64 = 4x4 MFMA. global_load_lds width-16 staging.
// ---------------------------------------------------------------------------
__device__ __forceinline__ void gemm128(const short* __restrict__ A,
                                        const short* __restrict__ B,
                                        int lda, int ldb, int kBeg, int kEnd,
                                        int l0, int f0,
                                        short* ldsA, short* ldsB,
                                        floatx4 acc[4][4]) {
    const int tid = threadIdx.x, lane = tid & 63, wid = tid >> 6;
    const int wm = wid & 1, wn = wid >> 1, quad = lane >> 4, l16 = lane & 15;
    const int r16 = lane >> 2, c8 = (lane & 3) * 8;
    for (int kt = kBeg; kt < kEnd; kt += 32) {
        __syncthreads();
#pragma unroll
        for (int p = 0; p < 2; p++) {
            int row = (wid + p * 4) * 16;
            gl_lds16(A + (size_t)(l0 + row + r16) * lda + kt + c8, ldsA + row * 32);
            gl_lds16(B + (size_t)(f0 + row + r16) * ldb + kt + c8, ldsB + row * 32);
        }
        __syncthreads();
        short8 a[4], b[4];
#pragma unroll
        for (int mi = 0; mi < 4; mi++)
            a[mi] = *(const short8*)&ldsA[(wm * 64 + mi * 16 + l16) * 32 + quad * 8];
#pragma unroll
        for (int ni = 0; ni < 4; ni++)
            b[ni] = *(const short8*)&ldsB[(wn * 64 + ni * 16 + l16) * 32 + quad * 8];
#pragma unroll
        for (int mi = 0; mi < 4; mi++)
#pragma unroll
            for (int ni = 0; ni < 4; ni++)
                acc[mi][ni] = __builtin_amdgcn_mfma_f32_16x16x32_bf16(a[mi], b[ni], acc[mi][ni], 0, 0, 0);
    }
}

// ---------------------------------------------------------------------------
// Kernel SCORES: P = exp(Q K^T / sqrt(512)) bf16 + row-sum atomics.
// 1D grid 2592; n = bx & 7 (XCD pin).
// ---------------------------------------------------------------------------
__global__ __launch_bounds__(256) void k_gemm_scores(const short* __restrict__ Q,
                                                     const short* __restrict__ Kb,
                                                     short* __restrict__ P,
                                                     float* __restrict__ lsum) {
    __shared__ __align__(16) short ldsA[128 * 32];
    __shared__ __align__(16) short ldsB[128 * 32];
    const int bx = blockIdx.x;
    const int n = bx & 7, t = bx >> 3;
    const int l0 = (t / 18) * 128, m0 = (t % 18) * 128;
    const short* A = Q + (size_t)n * L_DIM * D_DIM;
    const short* B = Kb + (size_t)n * L_DIM * D_DIM;
    const int lane = threadIdx.x & 63, wid = threadIdx.x >> 6;
    const int wm = wid & 1, wn = wid >> 1, quad = lane >> 4, l16 = lane & 15;

    floatx4 acc[4][4] = {};
    gemm128(A, B, 512, 512, 0, 512, l0, m0, ldsA, ldsB, acc);

    const float sc = 0.044194173824159216f;  // 1/sqrt(512)
    short* Pn = P + (size_t)n * L_DIM * L_DIM;
    float* ln = lsum + n * L_DIM;
#pragma unroll
    for (int mi = 0; mi < 4; mi++) {
#pragma unroll
        for (int r = 0; r < 4; r++) {
            int row = l0 + wm * 64 + mi * 16 + quad * 4 + r;
            float s = 0.f;
#pragma unroll
            for (int ni = 0; ni < 4; ni++) {
                int col = m0 + wn * 64 + ni * 16 + l16;
                unsigned short pb = f2bf(__expf(acc[mi][ni][r] * sc));
                Pn[(size_t)row * L_DIM + col] = (short)pb;
                s += bf2f(pb);  // denominator consistent with bf16-rounded P
            }
            s += __shfl_xor(s, 1);
            s += __shfl_xor(s, 2);
            s += __shfl_xor(s, 4);
            s += __shfl_xor(s, 8);
            if (l16 == 0) atomicAdd(&ln[row], s);
        }
    }
}

// ---------------------------------------------------------------------------
// Kernel OUT: out = (P @ V) / lsum. 1D grid 576; n = bx & 7. Inline dtype.
// ---------------------------------------------------------------------------
__global__ __launch_bounds__(256) void k_gemm_out(const short* __restrict__ P,
                                                  const short* __restrict__ Vt,
                                                  const float* __restrict__ lsum,
                                                  void* __restrict__ out_,
                                                  const unsigned short* __restrict__ xs) {
    __shared__ __align__(16) short ldsA[128 * 32];
    __shared__ __align__(16) short ldsB[128 * 32];
    const int fl = detect_f32(xs);
    const int bx = blockIdx.x;
    const int n = bx & 7, t = bx >> 3;
    const int l0 = (t >> 2) * 128, f0 = (t & 3) * 128;
    const short* A = P + (size_t)n * L_DIM * L_DIM;
    const short* B = Vt + (size_t)n * D_DIM * L_DIM;
    const int lane = threadIdx.x & 63, wid = threadIdx.x >> 6;
    const int wm = wid & 1, wn = wid >> 1, quad = lane >> 4, l16 = lane & 15;

    floatx4 acc[4][4] = {};
    gemm128(A, B, L_DIM, L_DIM, 0, L_DIM, l0, f0, ldsA, ldsB, acc);

#pragma unroll
    for (int mi = 0; mi < 4; mi++) {
#pragma unroll
        for (int r = 0; r < 4; r++) {
            int row = l0 + wm * 64 + mi * 16 + quad * 4 + r;
            float rl = 1.0f / lsum[n * L_DIM + row];
            if (fl) {
                float* out = (float*)out_;
#pragma unroll
                for (int ni = 0; ni < 4; ni++) {
                    int f = f0 + wn * 64 + ni * 16 + l16;
                    out[((size_t)n * L_DIM + row) * 512 + f] = acc[mi][ni][r] * rl;
                }
            } else {
                short* out = (short*)out_;
#pragma unroll
                for (int ni = 0; ni < 4; ni++) {
                    int f = f0 + wn * 64 + ni * 16 + l16;
                    out[((size_t)n * L_DIM + row) * 512 + f] = (short)f2bf(acc[mi][ni][r] * rl);
                }
            }
        }
    }
}

// ---------------------------------------------------------------------------
// FALLBACK path kernels (small ws): known-correct round-3/5 versions.
// ---------------------------------------------------------------------------
__global__ __launch_bounds__(256) void k_gemm_proj(const short* __restrict__ fx,
                                                   const short* __restrict__ Wc,
                                                   const short* __restrict__ bc,
                                                   short* __restrict__ Pbase) {
    __shared__ __align__(16) short ldsA[128 * 32];
    __shared__ __align__(16) short ldsB[128 * 32];
    const int bx = blockIdx.x;
    const int n = bx & 7, t = bx >> 3;
    const int proj = t / 72, tt = t % 72;
    const int l0 = (tt >> 2) * 128, f0 = (tt & 3) * 128;
    const short* A = fx + (size_t)n * L_DIM * D_DIM;
    const short* B = Wc + (size_t)proj * 262144;
    const short* bias = bc + proj * 512;
    short* P = Pbase + (size_t)proj * 8 * L_DIM * D_DIM + (size_t)n * L_DIM * D_DIM;
    const int lane = threadIdx.x & 63, wid = threadIdx.x >> 6;
    const int wm = wid & 1, wn = wid >> 1, quad = lane >> 4, l16 = lane & 15;
    floatx4 acc[4][4] = {};
    gemm128(A, B, 512, 512, 0, 512, l0, f0, ldsA, ldsB, acc);
#pragma unroll
    for (int ni = 0; ni < 4; ni++) {
        int f = f0 + wn * 64 + ni * 16 + l16;
        float bb = bf2f((unsigned short)bias[f]);
#pragma unroll
        for (int mi = 0; mi < 4; mi++)
#pragma unroll
            for (int r = 0; r < 4; r++) {
                int l = l0 + wm * 64 + mi * 16 + quad * 4 + r;
                P[(size_t)l * 512 + f] = (short)f2bf(tanhf(acc[mi][ni][r] + bb));
            }
    }
}

__global__ __launch_bounds__(256) void k_norm(short* __restrict__ base) {
    const int row = blockIdx.x * 4 + (threadIdx.x >> 6);
    const int lane = threadIdx.x & 63;
    short* p = base + (size_t)row * 512 + lane * 8;
    short8 v = *(const short8*)p;
    float x[8], s = 0.f, sq = 0.f;
#pragma unroll
    for (int j = 0; j < 8; j++) {
        x[j] = bf2f((unsigned short)v[j]);
        s += x[j]; sq += x[j] * x[j];
    }
#pragma unroll
    for (int m = 1; m < 64; m <<= 1) { s += __shfl_xor(s, m); sq += __shfl_xor(sq, m); }
    float mu = s * (1.0f / 512.0f);
    float var = sq * (1.0f / 512.0f) - mu * mu;
    float r1 = rsqrtf(var + 1e-5f);
    float y[8], s2 = 0.f, sq2 = 0.f;
#pragma unroll
    for (int j = 0; j < 8; j++) { y[j] = (x[j] - mu) * r1; s2 += y[j]; sq2 += y[j] * y[j]; }
#pragma unroll
    for (int m = 1; m < 64; m <<= 1) { s2 += __shfl_xor(s2, m); sq2 += __shfl_xor(sq2, m); }
    float mu2 = s2 * (1.0f / 512.0f);
    float var2 = sq2 * (1.0f / 512.0f) - mu2 * mu2;
    float r2 = rsqrtf(var2 + 1e-5f);
    short8 o;
#pragma unroll
    for (int j = 0; j < 8; j++) o[j] = (short)f2bf((y[j] - mu2) * r2);
    *(short8*)p = o;
}

__global__ __launch_bounds__(512) void k_attn(const short* __restrict__ Q,
                                              const short* __restrict__ K,
                                              const short* __restrict__ V,
                                              void* __restrict__ out_,
                                              const unsigned short* __restrict__ xs) {
    __shared__ __align__(16) short ldsKV[512 * 40];
    __shared__ __align__(16) short ldsP[64 * 40];
    __shared__ float ldsL[64];
    const int fl = detect_f32(xs);
    const int n = blockIdx.y;
    const int q0 = blockIdx.x * 64;
    const int tid = threadIdx.x, lane = tid & 63, wid = tid >> 6;
    const int wq = wid & 3, wk = wid >> 2, quad = lane >> 4, l16 = lane & 15;
    const short* Qn = Q + (size_t)n * L_DIM * 512;
    const short* Kn = K + (size_t)n * L_DIM * 512;
    const short* Vn = V + (size_t)n * L_DIM * 512;
    if (tid < 64) ldsL[tid] = 0.f;
    short8 qf[16];
#pragma unroll
    for (int fs = 0; fs < 16; fs++)
        qf[fs] = *(const short8*)(Qn + (size_t)(q0 + wq * 16 + l16) * 512 + fs * 32 + quad * 8);
    floatx4 acc[16] = {};
    const float sc = 0.044194173824159216f;
    for (int kt = 0; kt < 72; kt++) {
        const int key0 = kt * 32;
        __syncthreads();
#pragma unroll
        for (int p = 0; p < 4; p++) {
            int i = tid + p * 512;
            int row = i >> 6, c = (i & 63) * 8;
            *(short8*)&ldsKV[row * 520 + c] = *(const short8*)(Kn + (size_t)(key0 + row) * 512 + c);
        }
        __syncthreads();
        floatx4 sacc = {0.f, 0.f, 0.f, 0.f};
#pragma unroll
        for (int fs = 0; fs < 16; fs++) {
            short8 kf = *(const short8*)&ldsKV[(wk * 16 + l16) * 520 + fs * 32 + quad * 8];
            sacc = __builtin_amdgcn_mfma_f32_16x16x32_bf16(qf[fs], kf, sacc, 0, 0, 0);
        }
        float pe[4];
#pragma unroll
        for (int r = 0; r < 4; r++) {
            unsigned short pb = f2bf(__expf(sacc[r] * sc));
            ldsP[(wq * 16 + quad * 4 + r) * 40 + wk * 16 + l16] = (short)pb;
            pe[r] = bf2f(pb);
        }
#pragma unroll
        for (int r = 0; r < 4; r++) {
            float s = pe[r];
            s += __shfl_xor(s, 1); s += __shfl_xor(s, 2);
            s += __shfl_xor(s, 4); s += __shfl_xor(s, 8);
            if (l16 == 0) atomicAdd(&ldsL[wq * 16 + quad * 4 + r], s);
        }
        __syncthreads();
#pragma unroll
        for (int p = 0; p < 4; p++) {
            int i = tid + p * 512;
            int row = i >> 6, c = (i & 63) * 8;
            short8 v = *(const short8*)(Vn + (size_t)(key0 + row) * 512 + c);
#pragma unroll
            for (int j = 0; j < 8; j++) ldsKV[(c + j) * 40 + row] = v[j];
        }
        __syncthreads();
        short8 pf = *(const short8*)&ldsP[(wq * 16 + l16) * 40 + quad * 8];
#pragma unroll
        for (int ni = 0; ni < 16; ni++) {
            short8 vf = *(const short8*)&ldsKV[(wk * 256 + ni * 16 + l16) * 40 + quad * 8];
            acc[ni] = __builtin_amdgcn_mfma_f32_16x16x32_bf16(pf, vf, acc[ni], 0, 0, 0);
        }
    }
    __syncthreads();
    float rl[4];
#pragma unroll
    for (int r = 0; r < 4; r++) rl[r] = 1.0f / ldsL[wq * 16 + quad * 4 + r];
#pragma unroll
    for (int ni = 0; ni < 16; ni++) {
        int f = wk * 256 + ni * 16 + l16;
#pragma unroll
        for (int r = 0; r < 4; r++) {
            int q = q0 + wq * 16 + quad * 4 + r;
            if (fl) ((float*)out_)[((size_t)n * L_DIM + q) * 512 + f] = acc[ni][r] * rl[r];
            else ((short*)out_)[((size_t)n * L_DIM + q) * 512 + f] = (short)f2bf(acc[ni][r] * rl[r]);
        }
    }
}

extern "C" void kernel_launch(void* const* d_in, const int* in_sizes, int n_in,
                              void* d_out, int out_size, void* d_ws, size_t ws_size,
                              hipStream_t stream) {
    char* ws = (char*)d_ws;
    const size_t S1 = (size_t)8 * L_DIM * D_DIM * sizeof(short);  // 18,874,368
    short* Wc = (short*)(ws + 4096);
    short* bc = (short*)(ws + 4096 + 3 * 262144 * 2);
    short* flatX = (short*)(ws + 1581056);
    short* Pq = (short*)((char*)flatX + S1);
    short* Pk = (short*)((char*)Pq + S1);
    short* Pv = (short*)((char*)Pk + S1);   // fallback only
    short* Vt = (short*)((char*)Pv + S1);
    float* lsum = (float*)((char*)Vt + S1);
    short* P = (short*)((char*)lsum + 73728);
    const unsigned short* xs = (const unsigned short*)d_in[0];

    const size_t need = 1581056 + 5 * S1 + 73728 + (size_t)8 * L_DIM * L_DIM * 2;
    const bool big = ws_size >= need;

    k_pre<<<2761, 256, 0, stream>>>(d_in[1], d_in[3], d_in[5], d_in[2], d_in[4], d_in[6],
                                    d_in[0], xs, Wc, bc, lsum, flatX);
    if (big) {
        k_projnorm<<<864, 256, 0, stream>>>(flatX, Wc, bc, Pq, Pk, Vt);
        k_gemm_scores<<<2592, 256, 0, stream>>>(Pq, Pk, P, lsum);
        k_gemm_out<<<576, 256, 0, stream>>>(P, Vt, lsum, d_out, xs);
    } else {
        k_gemm_proj<<<1728, 256, 0, stream>>>(flatX, Wc, bc, Pq);
        k_norm<<<13824, 256, 0, stream>>>(Pq);
        k_attn<<<dim3(36, 8), 512, 0, stream>>>(Pq, Pk, Pv, d_out, xs);
    }
}